// Round 1
// baseline (378.783 us; speedup 1.0000x reference)
//
#include <hip/hip_runtime.h>
#include <math.h>

#define N_NODES 50000
#define N_EDGES 800000
#define HID 128
#define CAP 64                              // max in-degree; Poisson(16) -> P(>64) ~ 1e-18

// prep grid partition: [scatter | weight-cvt | h-cvt]
#define SCAT_TH   (N_EDGES / 8)             // 100000 threads, 8 edges each
#define SCAT_BLK  ((SCAT_TH + 255) / 256)   // 391
#define WCVT_BLK  64                        // 4 mats x 4096 float4 / 256
#define HCVT_BLK  (N_NODES * HID / 4 / 256) // 6250
#define PREP_BLK  (SCAT_BLK + WCVT_BLK + HCVT_BLK)

#define QKV_BX    ((N_NODES + 31) / 32)     // 1563
#define ATTN_BLK  ((N_NODES + 3) / 4)       // 12500
#define OUT_BLK   ((N_NODES + 63) / 64)     // 782

typedef _Float16 f16_t;
typedef f16_t f16x8 __attribute__((ext_vector_type(8)));
typedef f16_t f16x2 __attribute__((ext_vector_type(2)));
typedef float f32x4 __attribute__((ext_vector_type(4)));

__device__ __forceinline__ ushort f2h_bits(float x) {
    union { f16_t h; ushort u; } c; c.h = (f16_t)x; return c.u;
}
__device__ __forceinline__ f16x2 as_h2(uint u) {
    union { uint u_; f16x2 h; } c; c.u_ = u; return c.h;
}

// ---------------------------------------------------------------------------
// prep: one grid, three independent jobs co-scheduled.
//   blocks [0, SCAT_BLK)    : edge scatter — 8 edges/thread, int4 loads,
//                             8 independent returning atomics in flight,
//                             64B-padded counters
//   next WCVT_BLK           : Wq/Wk/Wv f32 -> f16 (hidden-k order);
//                             Wo f32 -> f16 with k-axis PERMUTED to head-major
//                             p = (k&7)*16 + (k>>3), matching attn's ao layout
//   next HCVT_BLK           : h f32 -> f16 (BW-bound; hides scatter latency)
__global__ __launch_bounds__(256) void prep(
    const float* __restrict__ h,
    const float* __restrict__ Wq, const float* __restrict__ Wk,
    const float* __restrict__ Wv, const float* __restrict__ Wo,
    ushort* __restrict__ hf, ushort* __restrict__ wf,     // wf: 4 mats concat
    const int* __restrict__ rows, const int* __restrict__ cols,
    int* __restrict__ cnt, ushort* __restrict__ slots)
{
    const int b = blockIdx.x;
    const int tid = threadIdx.x;

    if (b < SCAT_BLK) {
        const int t = b * 256 + tid;
        if (t < SCAT_TH) {
            const int4* r4 = (const int4*)rows + (size_t)t * 2;
            const int4* c4 = (const int4*)cols + (size_t)t * 2;
            int4 ra = r4[0], rb2 = r4[1];
            int4 ca = c4[0], cb = c4[1];
            const int r[8] = {ra.x, ra.y, ra.z, ra.w, rb2.x, rb2.y, rb2.z, rb2.w};
            const int c[8] = {ca.x, ca.y, ca.z, ca.w, cb.x, cb.y, cb.z, cb.w};
            int p[8];
#pragma unroll
            for (int u = 0; u < 8; ++u)
                p[u] = atomicAdd(&cnt[r[u] << 4], 1);     // 64B-padded counter
#pragma unroll
            for (int u = 0; u < 8; ++u)
                if (p[u] < CAP) slots[(size_t)r[u] * CAP + p[u]] = (ushort)c[u];
        }
    } else if (b < SCAT_BLK + WCVT_BLK) {
        const int t = (b - SCAT_BLK) * 256 + tid;         // [0, 16384)
        const int m = t >> 12, i = t & 4095;
        const float* src = (m == 0) ? Wq : (m == 1) ? Wk : (m == 2) ? Wv : Wo;
        float4 f = ((const float4*)src)[i];
        if (m < 3) {
            ushort4 o;
            o.x = f2h_bits(f.x); o.y = f2h_bits(f.y);
            o.z = f2h_bits(f.z); o.w = f2h_bits(f.w);
            ((ushort4*)(wf + m * 16384))[i] = o;
        } else {
            // Wo: permute k-axis to head-major p = head*16 + dim
            const int c  = i >> 5;            // output col (Wo row)
            const int k0 = (i & 31) * 4;      // hidden k of f.x; k0..k0+3 same dim group
            const int d  = k0 >> 3;           // all 4 share dim (k0 % 8 in {0,4})
            ushort* wo = wf + 3 * 16384 + c * HID + d;
            wo[((k0 + 0) & 7) << 4] = f2h_bits(f.x);
            wo[((k0 + 1) & 7) << 4] = f2h_bits(f.y);
            wo[((k0 + 2) & 7) << 4] = f2h_bits(f.z);
            wo[((k0 + 3) & 7) << 4] = f2h_bits(f.w);
        }
    } else {
        const int t = (b - SCAT_BLK - WCVT_BLK) * 256 + tid;  // [0, 1.6M)
        float4 f = ((const float4*)h)[t];
        ushort4 o;
        o.x = f2h_bits(f.x); o.y = f2h_bits(f.y);
        o.z = f2h_bits(f.z); o.w = f2h_bits(f.w);
        ((ushort4*)hf)[t] = o;
    }
}

// ---------------------------------------------------------------------------
// QKV projection, MFMA 16x16x32 f16, flat pipeline. One wave per 16-col set,
// 32 rows. Wave T (= HEAD) now owns cols c = 16*(mrow&7) + (mrow>=8)*8 + T:
// hidden col c = d*8 + h -> this wave covers all 16 dims of head T. The
// shfl_xor(8) pairing then packs (dim 2t | dim 2t+1) of head T, and the pack
// index p = 8*T + t gives a HEAD-MAJOR row layout:
//   qp[row*64 + 8h + t]  = [q_{2t} | q_{2t+1}] of head h (*0.25)
//   kv[row*64 + 8h + t]  = { [k_2t|k_2t+1], [v_2t|v_2t+1] } of head h
// Store addressing/coalescing identical to the previous (dim-major) version;
// only the W-fragment column gather changes (same 16-segment count, L2-hot).
__global__ __launch_bounds__(256) void gemm_qkv(
    const ushort* __restrict__ hf, const ushort* __restrict__ wf,
    const float* __restrict__ bq, const float* __restrict__ bk,
    const float* __restrict__ bv,
    uint* __restrict__ qp, uint2* __restrict__ kv)
{
    const int lane = threadIdx.x & 63;
    const int wid  = threadIdx.x >> 6;
    const int mrow = lane & 15;
    const int quad = lane >> 4;
    const int rb   = blockIdx.x * 32;
    const int T    = blockIdx.y * 4 + wid;               // head 0..7
    const int c    = ((mrow & 7) << 4) + ((mrow >> 3) << 3) + T;  // hidden col

    // A fragments (2 strips x 4 k-chunks), row-clamped at N
    f16x8 a[2][4];
#pragma unroll
    for (int s = 0; s < 2; ++s) {
        int ar = rb + s * 16 + mrow;
        if (ar >= N_NODES) ar = N_NODES - 1;
        const ushort* ap = hf + (size_t)ar * HID + quad * 8;
#pragma unroll
        for (int kc = 0; kc < 4; ++kc) a[s][kc] = *(const f16x8*)(ap + kc * 32);
    }
    // W fragments: all three mats, distinct registers
    f16x8 bQ[4], bK[4], bV[4];
#pragma unroll
    for (int kc = 0; kc < 4; ++kc) {
        const int off = c * HID + kc * 32 + quad * 8;
        bQ[kc] = *(const f16x8*)(wf + off);
        bK[kc] = *(const f16x8*)(wf + 16384 + off);
        bV[kc] = *(const f16x8*)(wf + 32768 + off);
    }

    f32x4 aq[2], ak[2], av[2];
#pragma unroll
    for (int s = 0; s < 2; ++s) {
        aq[s] = (f32x4){0.f, 0.f, 0.f, 0.f};
        ak[s] = (f32x4){0.f, 0.f, 0.f, 0.f};
        av[s] = (f32x4){0.f, 0.f, 0.f, 0.f};
    }
#pragma unroll
    for (int s = 0; s < 2; ++s)
#pragma unroll
        for (int kc = 0; kc < 4; ++kc) {
            aq[s] = __builtin_amdgcn_mfma_f32_16x16x32_f16(a[s][kc], bQ[kc], aq[s], 0, 0, 0);
            ak[s] = __builtin_amdgcn_mfma_f32_16x16x32_f16(a[s][kc], bK[kc], ak[s], 0, 0, 0);
            av[s] = __builtin_amdgcn_mfma_f32_16x16x32_f16(a[s][kc], bV[kc], av[s], 0, 0, 0);
        }

    const float bqc = bq[c], bkc = bk[c], bvc = bv[c];
    const bool  lo  = (mrow & 8) == 0;
    const int   i   = mrow & 7;                          // = dim-pair t
#pragma unroll
    for (int s = 0; s < 2; ++s)
#pragma unroll
        for (int r = 0; r < 4; ++r) {
            const int orow = rb + s * 16 + quad * 4 + r;
            uint qv = f2h_bits((aq[s][r] + bqc) * 0.25f);  // q pre-scaled 1/sqrt(d)
            uint kb = f2h_bits(ak[s][r] + bkc);
            uint vb = f2h_bits(av[s][r] + bvc);
            uint qh = __shfl_xor((int)qv, 8);
            uint kh = __shfl_xor((int)kb, 8);
            uint vh = __shfl_xor((int)vb, 8);
            if (lo && orow < N_NODES) {
                const size_t base = (size_t)orow * 64 + 8 * T + i;
                qp[base] = qv | (qh << 16);
                kv[base] = make_uint2(kb | (kh << 16), vb | (vh << 16));
            }
        }
}

// ---------------------------------------------------------------------------
// attn, head-per-lane structure. One wave per node; lane = (es, h) with
// es = lane>>3 (edge slot), h = lane&7 (head). Per 8-edge group each lane
// gathers 64 B of its edge's kv row (head h slice, k/v interleaved) and
// computes the FULL 16-dim head-h score with 8 chained v_dot2_f32_f16 —
// no per-edge cross-lane reduce, one exp per 8 edges. Softmax partials
// (l, O[16]) reduced across the 8 es-lanes ONCE per node at the end.
// Output ao is head-major (p = h*16 + d); gemm_out consumes it against the
// k-permuted Wo written by prep.
__global__ __launch_bounds__(256) void attn(
    const uint* __restrict__ qp, const uint2* __restrict__ kv,
    const int* __restrict__ cnt, const ushort* __restrict__ slots,
    ushort* __restrict__ ao)
{
    const int lane = threadIdx.x & 63;
    const int node = blockIdx.x * 4 + (threadIdx.x >> 6);
    if (node >= N_NODES) return;
    const int es = lane >> 3;
    const int h  = lane & 7;

    // q: head h, dims 0..15 (8 packed pairs, 32 B) — pre-scaled by 1/sqrt(d)
    const uint4* qb = (const uint4*)(qp + (size_t)node * 64 + h * 8);
    const uint4 q0 = qb[0], q1 = qb[1];

    int deg = cnt[node << 4];                  // padded counter
    if (deg > CAP) deg = CAP;
    const int myslot = (lane < deg) ? (int)slots[(size_t)node * CAP + lane] : 0;

    float l = 0.f;
    float O[16];
#pragma unroll
    for (int d = 0; d < 16; ++d) O[d] = 0.f;

    for (int j = 0; j < deg; j += 8) {
        const int sl = __shfl(myslot, j + es);             // j+es <= 63
        const uint4* kp = (const uint4*)(kv + (size_t)sl * 64 + h * 8);
        const uint4 r0 = kp[0], r1 = kp[1], r2 = kp[2], r3 = kp[3];
        // k elements: .x/.z of each uint4 (dims 0..15); v: .y/.w
        float s;
        s = __builtin_amdgcn_fdot2(as_h2(r0.x), as_h2(q0.x), 0.f, false);
        s = __builtin_amdgcn_fdot2(as_h2(r0.z), as_h2(q0.y), s, false);
        s = __builtin_amdgcn_fdot2(as_h2(r1.x), as_h2(q0.z), s, false);
        s = __builtin_amdgcn_fdot2(as_h2(r1.z), as_h2(q0.w), s, false);
        s = __builtin_amdgcn_fdot2(as_h2(r2.x), as_h2(q1.x), s, false);
        s = __builtin_amdgcn_fdot2(as_h2(r2.z), as_h2(q1.y), s, false);
        s = __builtin_amdgcn_fdot2(as_h2(r3.x), as_h2(q1.z), s, false);
        s = __builtin_amdgcn_fdot2(as_h2(r3.z), as_h2(q1.w), s, false);
        const float ex = ((j + es) < deg) ? __expf(s) : 0.f;
        l += ex;
        f16x2 v;
        v = as_h2(r0.y); O[0]  += ex * (float)v[0]; O[1]  += ex * (float)v[1];
        v = as_h2(r0.w); O[2]  += ex * (float)v[0]; O[3]  += ex * (float)v[1];
        v = as_h2(r1.y); O[4]  += ex * (float)v[0]; O[5]  += ex * (float)v[1];
        v = as_h2(r1.w); O[6]  += ex * (float)v[0]; O[7]  += ex * (float)v[1];
        v = as_h2(r2.y); O[8]  += ex * (float)v[0]; O[9]  += ex * (float)v[1];
        v = as_h2(r2.w); O[10] += ex * (float)v[0]; O[11] += ex * (float)v[1];
        v = as_h2(r3.y); O[12] += ex * (float)v[0]; O[13] += ex * (float)v[1];
        v = as_h2(r3.w); O[14] += ex * (float)v[0]; O[15] += ex * (float)v[1];
    }

    // reduce across the 8 es-lanes (lane bits 3..5), once per node
#pragma unroll
    for (int m = 8; m <= 32; m <<= 1) {
        l += __shfl_xor(l, m);
#pragma unroll
        for (int d = 0; d < 16; ++d) O[d] += __shfl_xor(O[d], m);
    }
    const float inv = (l > 0.f) ? 1.f / l : 0.f;   // deg-0 -> 0 (bo added later)

    // store head-major row: lanes es=0/1 write dims 0..7 / 8..15 (16 B each)
    if (es == 0) {
        uint4 st;
        st.x = (uint)f2h_bits(O[0] * inv) | ((uint)f2h_bits(O[1] * inv) << 16);
        st.y = (uint)f2h_bits(O[2] * inv) | ((uint)f2h_bits(O[3] * inv) << 16);
        st.z = (uint)f2h_bits(O[4] * inv) | ((uint)f2h_bits(O[5] * inv) << 16);
        st.w = (uint)f2h_bits(O[6] * inv) | ((uint)f2h_bits(O[7] * inv) << 16);
        *(uint4*)(ao + (size_t)node * HID + h * 16) = st;
    } else if (es == 1) {
        uint4 st;
        st.x = (uint)f2h_bits(O[8]  * inv) | ((uint)f2h_bits(O[9]  * inv) << 16);
        st.y = (uint)f2h_bits(O[10] * inv) | ((uint)f2h_bits(O[11] * inv) << 16);
        st.z = (uint)f2h_bits(O[12] * inv) | ((uint)f2h_bits(O[13] * inv) << 16);
        st.w = (uint)f2h_bits(O[14] * inv) | ((uint)f2h_bits(O[15] * inv) << 16);
        *(uint4*)(ao + (size_t)node * HID + h * 16 + 8) = st;
    }
}

// ---------------------------------------------------------------------------
// Output projection, flat pipeline: all 24 loads (16 A + 8 W f16) up front,
// then 32 MFMAs. 64-row blocks, wave owns 2 n-tiles (32 cols).
// A (ao) is head-major in k; wfo is the k-permuted Wo from prep — the MFMA
// contraction index just runs over the permuted order on both sides.
__global__ __launch_bounds__(256) void gemm_out(
    const ushort* __restrict__ A, const ushort* __restrict__ wfo,
    const float* __restrict__ bias, float* __restrict__ out)
{
    const int lane = threadIdx.x & 63;
    const int wid  = threadIdx.x >> 6;
    const int mrow = lane & 15;
    const int quad = lane >> 4;
    const int rb   = blockIdx.x * 64;

    const int c0 = wid * 32 + mrow;
    const int c1 = c0 + 16;

    f16x8 a[4][4];
#pragma unroll
    for (int s = 0; s < 4; ++s) {
        int ar = rb + s * 16 + mrow;
        if (ar >= N_NODES) ar = N_NODES - 1;
        const ushort* ap = A + (size_t)ar * HID + quad * 8;
#pragma unroll
        for (int kc = 0; kc < 4; ++kc) a[s][kc] = *(const f16x8*)(ap + kc * 32);
    }
    f16x8 b0[4], b1[4];
#pragma unroll
    for (int kc = 0; kc < 4; ++kc) {
        b0[kc] = *(const f16x8*)(wfo + c0 * HID + kc * 32 + quad * 8);
        b1[kc] = *(const f16x8*)(wfo + c1 * HID + kc * 32 + quad * 8);
    }

    f32x4 acc[4][2];
#pragma unroll
    for (int s = 0; s < 4; ++s) {
        acc[s][0] = (f32x4){0.f, 0.f, 0.f, 0.f};
        acc[s][1] = (f32x4){0.f, 0.f, 0.f, 0.f};
    }
#pragma unroll
    for (int s = 0; s < 4; ++s)
#pragma unroll
        for (int kc = 0; kc < 4; ++kc) {
            acc[s][0] = __builtin_amdgcn_mfma_f32_16x16x32_f16(a[s][kc], b0[kc], acc[s][0], 0, 0, 0);
            acc[s][1] = __builtin_amdgcn_mfma_f32_16x16x32_f16(a[s][kc], b1[kc], acc[s][1], 0, 0, 0);
        }

    const float bc0 = bias[c0], bc1 = bias[c1];
#pragma unroll
    for (int s = 0; s < 4; ++s)
#pragma unroll
        for (int r = 0; r < 4; ++r) {
            const int orow = rb + s * 16 + quad * 4 + r;
            if (orow < N_NODES) {
                out[(size_t)orow * HID + c0] = acc[s][0][r] + bc0;
                out[(size_t)orow * HID + c1] = acc[s][1][r] + bc1;
            }
        }
}

// ---------------------------------------------------------------------------
extern "C" void kernel_launch(void* const* d_in, const int* in_sizes, int n_in,
                              void* d_out, int out_size, void* d_ws, size_t ws_size,
                              hipStream_t stream)
{
    const float* h    = (const float*)d_in[0];
    const int*   rows = (const int*)  d_in[1];
    const int*   cols = (const int*)  d_in[2];
    const float* Wq   = (const float*)d_in[3];
    const float* bq   = (const float*)d_in[4];
    const float* Wk   = (const float*)d_in[5];
    const float* bk   = (const float*)d_in[6];
    const float* Wv   = (const float*)d_in[7];
    const float* bv   = (const float*)d_in[8];
    const float* Wo   = (const float*)d_in[9];
    const float* bo   = (const float*)d_in[10];
    float* out = (float*)d_out;

    char* ws = (char*)d_ws;
    uint*   qp    = (uint*)ws;    ws += (size_t)N_NODES * 64 * 4;   // 12.8 MB
    uint2*  kv    = (uint2*)ws;   ws += (size_t)N_NODES * 64 * 8;   // 25.6 MB
    ushort* hf    = (ushort*)ws;  ws += (size_t)N_NODES * HID * 2;  // 12.8 MB
    ushort* ao    = (ushort*)ws;  ws += (size_t)N_NODES * HID * 2;  // 12.8 MB
    ushort* wf    = (ushort*)ws;  ws += 4 * 16384 * 2;              // 128 KB
    int*    cnt   = (int*)ws;     ws += (size_t)N_NODES * 64;       // 3.2 MB padded
    ushort* slots = (ushort*)ws;  // N*CAP ushorts, 6.4 MB

    hipMemsetAsync(cnt, 0, (size_t)N_NODES * 64, stream);

    dim3 blk(256);
    prep<<<PREP_BLK, blk, 0, stream>>>(h, Wq, Wk, Wv, Wo, hf, wf,
                                       rows, cols, cnt, slots);
    gemm_qkv<<<dim3(QKV_BX, 2), blk, 0, stream>>>(hf, wf, bq, bk, bv, qp, kv);
    attn<<<ATTN_BLK, blk, 0, stream>>>(qp, kv, cnt, slots, ao);
    gemm_out<<<OUT_BLK, blk, 0, stream>>>(ao, wf + 3 * 16384, bo, out);
}

// Round 2
// 238.376 us; speedup vs baseline: 1.5890x; 1.5890x over previous
//
#include <hip/hip_runtime.h>
#include <math.h>

#define N_NODES 50000
#define N_EDGES 800000
#define HID 128
#define CAP 64                              // max in-degree; Poisson(16) -> P(>64) ~ 1e-18

// prep grid partition: [scatter | weight-cvt | h-cvt]
#define SCAT_TH   (N_EDGES / 8)             // 100000 threads, 8 edges each
#define SCAT_BLK  ((SCAT_TH + 255) / 256)   // 391
#define WCVT_BLK  64                        // 4 mats x 4096 float4 / 256
#define HCVT_BLK  (N_NODES * HID / 4 / 256) // 6250
#define PREP_BLK  (SCAT_BLK + WCVT_BLK + HCVT_BLK)

#define QKV_BX    ((N_NODES + 31) / 32)     // 1563
#define ATTN_BLK  ((N_NODES + 3) / 4)       // 12500
#define OUT_BLK   ((N_NODES + 63) / 64)     // 782

typedef _Float16 f16_t;
typedef f16_t f16x8 __attribute__((ext_vector_type(8)));
typedef f16_t f16x2 __attribute__((ext_vector_type(2)));
typedef float f32x4 __attribute__((ext_vector_type(4)));

__device__ __forceinline__ ushort f2h_bits(float x) {
    union { f16_t h; ushort u; } c; c.h = (f16_t)x; return c.u;
}
__device__ __forceinline__ f16x2 as_h2(uint u) {
    union { uint u_; f16x2 h; } c; c.u_ = u; return c.h;
}

// ---------------------------------------------------------------------------
// prep: one grid, three independent jobs co-scheduled.
//   blocks [0, SCAT_BLK)    : edge scatter — 8 edges/thread, int4 loads,
//                             8 independent returning atomics in flight,
//                             64B-padded counters
//   next WCVT_BLK           : Wq/Wk/Wv f32 -> f16 (hidden-k order);
//                             Wo f32 -> f16 with k-axis PERMUTED to head-major
//                             p = (k&7)*16 + (k>>3), matching attn's ao layout
//   next HCVT_BLK           : h f32 -> f16 (BW-bound; hides scatter latency)
__global__ __launch_bounds__(256) void prep(
    const float* __restrict__ h,
    const float* __restrict__ Wq, const float* __restrict__ Wk,
    const float* __restrict__ Wv, const float* __restrict__ Wo,
    ushort* __restrict__ hf, ushort* __restrict__ wf,     // wf: 4 mats concat
    const int* __restrict__ rows, const int* __restrict__ cols,
    int* __restrict__ cnt, ushort* __restrict__ slots)
{
    const int b = blockIdx.x;
    const int tid = threadIdx.x;

    if (b < SCAT_BLK) {
        const int t = b * 256 + tid;
        if (t < SCAT_TH) {
            const int4* r4 = (const int4*)rows + (size_t)t * 2;
            const int4* c4 = (const int4*)cols + (size_t)t * 2;
            int4 ra = r4[0], rb2 = r4[1];
            int4 ca = c4[0], cb = c4[1];
            const int r[8] = {ra.x, ra.y, ra.z, ra.w, rb2.x, rb2.y, rb2.z, rb2.w};
            const int c[8] = {ca.x, ca.y, ca.z, ca.w, cb.x, cb.y, cb.z, cb.w};
            int p[8];
#pragma unroll
            for (int u = 0; u < 8; ++u)
                p[u] = atomicAdd(&cnt[r[u] << 4], 1);     // 64B-padded counter
#pragma unroll
            for (int u = 0; u < 8; ++u)
                if (p[u] < CAP) slots[(size_t)r[u] * CAP + p[u]] = (ushort)c[u];
        }
    } else if (b < SCAT_BLK + WCVT_BLK) {
        const int t = (b - SCAT_BLK) * 256 + tid;         // [0, 16384)
        const int m = t >> 12, i = t & 4095;
        const float* src = (m == 0) ? Wq : (m == 1) ? Wk : (m == 2) ? Wv : Wo;
        float4 f = ((const float4*)src)[i];
        if (m < 3) {
            ushort4 o;
            o.x = f2h_bits(f.x); o.y = f2h_bits(f.y);
            o.z = f2h_bits(f.z); o.w = f2h_bits(f.w);
            ((ushort4*)(wf + m * 16384))[i] = o;
        } else {
            // Wo: permute k-axis to head-major p = head*16 + dim
            const int c  = i >> 5;            // output col (Wo row)
            const int k0 = (i & 31) * 4;      // hidden k of f.x; k0..k0+3 same dim group
            const int d  = k0 >> 3;           // all 4 share dim (k0 % 8 in {0,4})
            ushort* wo = wf + 3 * 16384 + c * HID + d;
            wo[((k0 + 0) & 7) << 4] = f2h_bits(f.x);
            wo[((k0 + 1) & 7) << 4] = f2h_bits(f.y);
            wo[((k0 + 2) & 7) << 4] = f2h_bits(f.z);
            wo[((k0 + 3) & 7) << 4] = f2h_bits(f.w);
        }
    } else {
        const int t = (b - SCAT_BLK - WCVT_BLK) * 256 + tid;  // [0, 1.6M)
        float4 f = ((const float4*)h)[t];
        ushort4 o;
        o.x = f2h_bits(f.x); o.y = f2h_bits(f.y);
        o.z = f2h_bits(f.z); o.w = f2h_bits(f.w);
        ((ushort4*)hf)[t] = o;
    }
}

// ---------------------------------------------------------------------------
// QKV projection, MFMA 16x16x32 f16, flat pipeline. One wave per 16-col set,
// 32 rows. Wave T (= HEAD) owns cols c = 16*(mrow&7) + (mrow>=8)*8 + T:
// hidden col c = d*8 + h -> this wave covers all 16 dims of head T. The
// shfl_xor(8) pairing packs (dim 2t | dim 2t+1) of head T, and the pack
// index p = 8*T + t gives a HEAD-MAJOR row layout:
//   qp[row*64 + 8h + t]  = [q_{2t} | q_{2t+1}] of head h (*0.25)
//   kv[row*64 + 8h + t]  = { [k_2t|k_2t+1], [v_2t|v_2t+1] } of head h
__global__ __launch_bounds__(256) void gemm_qkv(
    const ushort* __restrict__ hf, const ushort* __restrict__ wf,
    const float* __restrict__ bq, const float* __restrict__ bk,
    const float* __restrict__ bv,
    uint* __restrict__ qp, uint2* __restrict__ kv)
{
    const int lane = threadIdx.x & 63;
    const int wid  = threadIdx.x >> 6;
    const int mrow = lane & 15;
    const int quad = lane >> 4;
    const int rb   = blockIdx.x * 32;
    const int T    = blockIdx.y * 4 + wid;               // head 0..7
    const int c    = ((mrow & 7) << 4) + ((mrow >> 3) << 3) + T;  // hidden col

    // A fragments (2 strips x 4 k-chunks), row-clamped at N
    f16x8 a[2][4];
#pragma unroll
    for (int s = 0; s < 2; ++s) {
        int ar = rb + s * 16 + mrow;
        if (ar >= N_NODES) ar = N_NODES - 1;
        const ushort* ap = hf + (size_t)ar * HID + quad * 8;
#pragma unroll
        for (int kc = 0; kc < 4; ++kc) a[s][kc] = *(const f16x8*)(ap + kc * 32);
    }
    // W fragments: all three mats, distinct registers
    f16x8 bQ[4], bK[4], bV[4];
#pragma unroll
    for (int kc = 0; kc < 4; ++kc) {
        const int off = c * HID + kc * 32 + quad * 8;
        bQ[kc] = *(const f16x8*)(wf + off);
        bK[kc] = *(const f16x8*)(wf + 16384 + off);
        bV[kc] = *(const f16x8*)(wf + 32768 + off);
    }

    f32x4 aq[2], ak[2], av[2];
#pragma unroll
    for (int s = 0; s < 2; ++s) {
        aq[s] = (f32x4){0.f, 0.f, 0.f, 0.f};
        ak[s] = (f32x4){0.f, 0.f, 0.f, 0.f};
        av[s] = (f32x4){0.f, 0.f, 0.f, 0.f};
    }
#pragma unroll
    for (int s = 0; s < 2; ++s)
#pragma unroll
        for (int kc = 0; kc < 4; ++kc) {
            aq[s] = __builtin_amdgcn_mfma_f32_16x16x32_f16(a[s][kc], bQ[kc], aq[s], 0, 0, 0);
            ak[s] = __builtin_amdgcn_mfma_f32_16x16x32_f16(a[s][kc], bK[kc], ak[s], 0, 0, 0);
            av[s] = __builtin_amdgcn_mfma_f32_16x16x32_f16(a[s][kc], bV[kc], av[s], 0, 0, 0);
        }

    const float bqc = bq[c], bkc = bk[c], bvc = bv[c];
    const bool  lo  = (mrow & 8) == 0;
    const int   i   = mrow & 7;                          // = dim-pair t
#pragma unroll
    for (int s = 0; s < 2; ++s)
#pragma unroll
        for (int r = 0; r < 4; ++r) {
            const int orow = rb + s * 16 + quad * 4 + r;
            uint qv = f2h_bits((aq[s][r] + bqc) * 0.25f);  // q pre-scaled 1/sqrt(d)
            uint kb = f2h_bits(ak[s][r] + bkc);
            uint vb = f2h_bits(av[s][r] + bvc);
            uint qh = __shfl_xor((int)qv, 8);
            uint kh = __shfl_xor((int)kb, 8);
            uint vh = __shfl_xor((int)vb, 8);
            if (lo && orow < N_NODES) {
                const size_t base = (size_t)orow * 64 + 8 * T + i;
                qp[base] = qv | (qh << 16);
                kv[base] = make_uint2(kb | (kh << 16), vb | (vh << 16));
            }
        }
}

// ---------------------------------------------------------------------------
// attn, hybrid structure (round-1 post-mortem: per-lane 64B gather touched 64
// cache lines/instr and reg-capped serial loads -> latency-bound at 12% HBM).
// Lane = (half, t): half = lane>>5 picks which edge of a pair, t = lane&31
// owns the row's uint4 slot t = dim-pairs (2t, 2t+1) = head t>>2, dims
// 4(t&3)..4(t&3)+3. 32 lanes read one FULL 512 B kv row contiguously
// (16 lines / 2 rows per load instr — round-0 line efficiency), wave covers
// 2 edges per load. Head = 4-lane quad -> butterfly is 2 shfls (xor 1,2).
// 8-edge unroll, 4 independent register banks keeps 4 loads in flight.
__device__ __forceinline__ void pair_acc(uint4 rr, uint2 qu,
                                         float& l, float* O)
{
    float p = __builtin_amdgcn_fdot2(as_h2(rr.x), as_h2(qu.x), 0.f, false);
    p = __builtin_amdgcn_fdot2(as_h2(rr.z), as_h2(qu.y), p, false);
    p += __shfl_xor(p, 1);
    p += __shfl_xor(p, 2);
    const float ex = __expf(p);
    l += ex;
    const f16x2 va = as_h2(rr.y), vb = as_h2(rr.w);
    O[0] += ex * (float)va[0];
    O[1] += ex * (float)va[1];
    O[2] += ex * (float)vb[0];
    O[3] += ex * (float)vb[1];
}

__device__ __forceinline__ void pair_acc_m(uint4 rr, uint2 qu, bool ok,
                                           float& l, float* O)
{
    float p = __builtin_amdgcn_fdot2(as_h2(rr.x), as_h2(qu.x), 0.f, false);
    p = __builtin_amdgcn_fdot2(as_h2(rr.z), as_h2(qu.y), p, false);
    p += __shfl_xor(p, 1);
    p += __shfl_xor(p, 2);
    const float ex = ok ? __expf(p) : 0.f;
    l += ex;
    const f16x2 va = as_h2(rr.y), vb = as_h2(rr.w);
    O[0] += ex * (float)va[0];
    O[1] += ex * (float)va[1];
    O[2] += ex * (float)vb[0];
    O[3] += ex * (float)vb[1];
}

__global__ __launch_bounds__(256) void attn(
    const uint* __restrict__ qp, const uint2* __restrict__ kv,
    const int* __restrict__ cnt, const ushort* __restrict__ slots,
    ushort* __restrict__ ao)
{
    const int lane = threadIdx.x & 63;
    const int node = blockIdx.x * 4 + (threadIdx.x >> 6);
    if (node >= N_NODES) return;
    const int half = lane >> 5;              // edge-of-pair selector
    const int t    = lane & 31;              // uint4 slot in row

    // q dim-pairs (2t, 2t+1): head t>>2, dims 4(t&3)..+3 (pre-scaled)
    const uint2 qu = *(const uint2*)(qp + (size_t)node * 64 + 2 * t);

    int deg = cnt[node << 4];                // padded counter
    if (deg > CAP) deg = CAP;
    const int myslot = (lane < deg) ? (int)slots[(size_t)node * CAP + lane] : 0;

    float l0 = 0.f, l1 = 0.f, l2 = 0.f, l3 = 0.f;
    float O0[4] = {0,0,0,0}, O1[4] = {0,0,0,0};
    float O2[4] = {0,0,0,0}, O3[4] = {0,0,0,0};

    const uint4* base = (const uint4*)kv;    // row = 32 uint4

    int j = 0;
    for (; j + 8 <= deg; j += 8) {
        const int s0 = __shfl(myslot, j + half);
        const int s1 = __shfl(myslot, j + 2 + half);
        const int s2 = __shfl(myslot, j + 4 + half);
        const int s3 = __shfl(myslot, j + 6 + half);
        const uint4 r0 = base[(size_t)s0 * 32 + t];
        const uint4 r1 = base[(size_t)s1 * 32 + t];
        const uint4 r2 = base[(size_t)s2 * 32 + t];
        const uint4 r3 = base[(size_t)s3 * 32 + t];
        pair_acc(r0, qu, l0, O0);
        pair_acc(r1, qu, l1, O1);
        pair_acc(r2, qu, l2, O2);
        pair_acc(r3, qu, l3, O3);
    }
    for (; j < deg; j += 2) {
        const int e = j + half;
        const int s = __shfl(myslot, e);     // e<=deg<=64: wraps to lane 0, masked below
        const uint4 rr = base[(size_t)s * 32 + t];
        pair_acc_m(rr, qu, e < deg, l0, O0);
    }

    float l = (l0 + l1) + (l2 + l3);
    float Of[4];
    Of[0] = (O0[0] + O1[0]) + (O2[0] + O3[0]);
    Of[1] = (O0[1] + O1[1]) + (O2[1] + O3[1]);
    Of[2] = (O0[2] + O1[2]) + (O2[2] + O3[2]);
    Of[3] = (O0[3] + O1[3]) + (O2[3] + O3[3]);

    // merge the two halves (each processed its own edge subset)
    l += __shfl_xor(l, 32);
    Of[0] += __shfl_xor(Of[0], 32);
    Of[1] += __shfl_xor(Of[1], 32);
    Of[2] += __shfl_xor(Of[2], 32);
    Of[3] += __shfl_xor(Of[3], 32);

    const float inv = (l > 0.f) ? 1.f / l : 0.f;   // deg-0 -> 0 (bo added later)

    if (half == 0) {                        // lanes 0..31 store 8 B each, contiguous
        ushort4 st;
        st.x = f2h_bits(Of[0] * inv);
        st.y = f2h_bits(Of[1] * inv);
        st.z = f2h_bits(Of[2] * inv);
        st.w = f2h_bits(Of[3] * inv);
        *(ushort4*)(ao + (size_t)node * HID + 4 * t) = st;
    }
}

// ---------------------------------------------------------------------------
// Output projection, flat pipeline: all 24 loads (16 A + 8 W f16) up front,
// then 32 MFMAs. 64-row blocks, wave owns 2 n-tiles (32 cols).
// A (ao) is head-major in k; wfo is the k-permuted Wo from prep — the MFMA
// contraction index just runs over the permuted order on both sides.
__global__ __launch_bounds__(256) void gemm_out(
    const ushort* __restrict__ A, const ushort* __restrict__ wfo,
    const float* __restrict__ bias, float* __restrict__ out)
{
    const int lane = threadIdx.x & 63;
    const int wid  = threadIdx.x >> 6;
    const int mrow = lane & 15;
    const int quad = lane >> 4;
    const int rb   = blockIdx.x * 64;

    const int c0 = wid * 32 + mrow;
    const int c1 = c0 + 16;

    f16x8 a[4][4];
#pragma unroll
    for (int s = 0; s < 4; ++s) {
        int ar = rb + s * 16 + mrow;
        if (ar >= N_NODES) ar = N_NODES - 1;
        const ushort* ap = A + (size_t)ar * HID + quad * 8;
#pragma unroll
        for (int kc = 0; kc < 4; ++kc) a[s][kc] = *(const f16x8*)(ap + kc * 32);
    }
    f16x8 b0[4], b1[4];
#pragma unroll
    for (int kc = 0; kc < 4; ++kc) {
        b0[kc] = *(const f16x8*)(wfo + c0 * HID + kc * 32 + quad * 8);
        b1[kc] = *(const f16x8*)(wfo + c1 * HID + kc * 32 + quad * 8);
    }

    f32x4 acc[4][2];
#pragma unroll
    for (int s = 0; s < 4; ++s) {
        acc[s][0] = (f32x4){0.f, 0.f, 0.f, 0.f};
        acc[s][1] = (f32x4){0.f, 0.f, 0.f, 0.f};
    }
#pragma unroll
    for (int s = 0; s < 4; ++s)
#pragma unroll
        for (int kc = 0; kc < 4; ++kc) {
            acc[s][0] = __builtin_amdgcn_mfma_f32_16x16x32_f16(a[s][kc], b0[kc], acc[s][0], 0, 0, 0);
            acc[s][1] = __builtin_amdgcn_mfma_f32_16x16x32_f16(a[s][kc], b1[kc], acc[s][1], 0, 0, 0);
        }

    const float bc0 = bias[c0], bc1 = bias[c1];
#pragma unroll
    for (int s = 0; s < 4; ++s)
#pragma unroll
        for (int r = 0; r < 4; ++r) {
            const int orow = rb + s * 16 + quad * 4 + r;
            if (orow < N_NODES) {
                out[(size_t)orow * HID + c0] = acc[s][0][r] + bc0;
                out[(size_t)orow * HID + c1] = acc[s][1][r] + bc1;
            }
        }
}

// ---------------------------------------------------------------------------
extern "C" void kernel_launch(void* const* d_in, const int* in_sizes, int n_in,
                              void* d_out, int out_size, void* d_ws, size_t ws_size,
                              hipStream_t stream)
{
    const float* h    = (const float*)d_in[0];
    const int*   rows = (const int*)  d_in[1];
    const int*   cols = (const int*)  d_in[2];
    const float* Wq   = (const float*)d_in[3];
    const float* bq   = (const float*)d_in[4];
    const float* Wk   = (const float*)d_in[5];
    const float* bk   = (const float*)d_in[6];
    const float* Wv   = (const float*)d_in[7];
    const float* bv   = (const float*)d_in[8];
    const float* Wo   = (const float*)d_in[9];
    const float* bo   = (const float*)d_in[10];
    float* out = (float*)d_out;

    char* ws = (char*)d_ws;
    uint*   qp    = (uint*)ws;    ws += (size_t)N_NODES * 64 * 4;   // 12.8 MB
    uint2*  kv    = (uint2*)ws;   ws += (size_t)N_NODES * 64 * 8;   // 25.6 MB
    ushort* hf    = (ushort*)ws;  ws += (size_t)N_NODES * HID * 2;  // 12.8 MB
    ushort* ao    = (ushort*)ws;  ws += (size_t)N_NODES * HID * 2;  // 12.8 MB
    ushort* wf    = (ushort*)ws;  ws += 4 * 16384 * 2;              // 128 KB
    int*    cnt   = (int*)ws;     ws += (size_t)N_NODES * 64;       // 3.2 MB padded
    ushort* slots = (ushort*)ws;  // N*CAP ushorts, 6.4 MB

    hipMemsetAsync(cnt, 0, (size_t)N_NODES * 64, stream);

    dim3 blk(256);
    prep<<<PREP_BLK, blk, 0, stream>>>(h, Wq, Wk, Wv, Wo, hf, wf,
                                       rows, cols, cnt, slots);
    gemm_qkv<<<dim3(QKV_BX, 2), blk, 0, stream>>>(hf, wf, bq, bk, bv, qp, kv);
    attn<<<ATTN_BLK, blk, 0, stream>>>(qp, kv, cnt, slots, ao);
    gemm_out<<<OUT_BLK, blk, 0, stream>>>(ao, wf + 3 * 16384, bo, out);
}